// Round 4
// baseline (1427.550 us; speedup 1.0000x reference)
//
#include <hip/hip_runtime.h>
#include <hip/hip_bf16.h>

// BinaryLinear: C[M,N] = (x[M,K] @ sign(W)[N,K]^T) * scale + bias
// M=8192 K=4096 N=16384 fp32. Binarize W -> +-1 bf16, round x -> bf16,
// bf16 MFMA GEMM. Round 4: free-running K-tile body. Full-tile publication
// (stage all of tile t+1 at top of tile t), only 2 barriers per K-tile with
// NOTHING between them but per-wave work; wave role rotation (odd waves do
// K-half1 first) so LDS-read bursts of half the waves overlap MFMA bursts
// of the other half; deep vmcnt (full K-tile); setprio around MFMA.

typedef __attribute__((ext_vector_type(4))) float f32x4;
typedef __attribute__((ext_vector_type(8))) short s16x8;
typedef __attribute__((ext_vector_type(4))) unsigned int u32x4;

#define AS1(p) ((const __attribute__((address_space(1))) void*)(p))
#define AS3(p) ((__attribute__((address_space(3))) void*)(p))

__device__ __forceinline__ unsigned short f2bf(float f) {
  unsigned u = __float_as_uint(f);
  u += 0x7FFFu + ((u >> 16) & 1u);
  return (unsigned short)(u >> 16);
}

__global__ void __launch_bounds__(256) cvt_f32_bf16(const float* __restrict__ in,
                                                    unsigned short* __restrict__ out,
                                                    int n8) {
  int i = blockIdx.x * 256 + threadIdx.x;
  const int stride = gridDim.x * 256;
  for (; i < n8; i += stride) {
    const f32x4* p = (const f32x4*)in + (size_t)i * 2;
    f32x4 v0 = p[0], v1 = p[1];
    s16x8 o;
    o[0] = (short)f2bf(v0[0]); o[1] = (short)f2bf(v0[1]);
    o[2] = (short)f2bf(v0[2]); o[3] = (short)f2bf(v0[3]);
    o[4] = (short)f2bf(v1[0]); o[5] = (short)f2bf(v1[1]);
    o[6] = (short)f2bf(v1[2]); o[7] = (short)f2bf(v1[3]);
    *(s16x8*)(out + (size_t)i * 8) = o;
  }
}

__global__ void __launch_bounds__(256) bin_f32_bf16(const unsigned int* __restrict__ in,
                                                    unsigned short* __restrict__ out,
                                                    int n8) {
  int i = blockIdx.x * 256 + threadIdx.x;
  const int stride = gridDim.x * 256;
  for (; i < n8; i += stride) {
    const u32x4* p = (const u32x4*)in + (size_t)i * 2;
    u32x4 v0 = p[0], v1 = p[1];
    s16x8 o;  // bf16 +-1.0 from fp32 sign bit
    o[0] = (short)(0x3F80u | ((v0[0] >> 16) & 0x8000u));
    o[1] = (short)(0x3F80u | ((v0[1] >> 16) & 0x8000u));
    o[2] = (short)(0x3F80u | ((v0[2] >> 16) & 0x8000u));
    o[3] = (short)(0x3F80u | ((v0[3] >> 16) & 0x8000u));
    o[4] = (short)(0x3F80u | ((v1[0] >> 16) & 0x8000u));
    o[5] = (short)(0x3F80u | ((v1[1] >> 16) & 0x8000u));
    o[6] = (short)(0x3F80u | ((v1[2] >> 16) & 0x8000u));
    o[7] = (short)(0x3F80u | ((v1[3] >> 16) & 0x8000u));
    *(s16x8*)(out + (size_t)i * 8) = o;
  }
}

// ---------------------------------------------------------------------------
// 256x256 tile, BK=64, 512 threads = 8 waves (2M x 4N), wave tile 128x64.
// LDS (128 KiB): buf{0,1} x op{A,B} x Khalf{0,1} regions of 256 rows x 64 B.
//   byte = buf*65536 + op*32768 + h*16384 + row*64 + (kc ^ ((row>>1)&3))*16
// Stage: global_load_lds w=16, linear dest, inverse-swizzled source (rule #21).
// Per K-tile: [stage full tile t+1 (8 loads)] [2 free-running sub-steps of
// {12 ds_read_b128 + 32 MFMA}, K-half order rotated by wave parity]
// [vmcnt(0): retires loads issued a full tile ago] [barrier: publish].
// ---------------------------------------------------------------------------

#define WAITV0() asm volatile("s_waitcnt vmcnt(0)" ::: "memory")
#define BAR()    __builtin_amdgcn_s_barrier()
#define PRIO(x)  __builtin_amdgcn_s_setprio(x)

#define LDSB ((const char*)lds)

// kso: runtime byte offset of the K-half region (0 or 16384)
#define LOADSUB(kso)                                                           \
  do {                                                                         \
    _Pragma("unroll") for (int mi = 0; mi < 4; ++mi)                           \
        a0[mi] = *(const s16x8*)(LDSB + bufR + rdA + (kso) + mi * 1024);       \
    _Pragma("unroll") for (int ni = 0; ni < 4; ++ni)                           \
        b0[ni] = *(const s16x8*)(LDSB + bufR + rdB + (kso) + ni * 1024);       \
    _Pragma("unroll") for (int mi = 0; mi < 4; ++mi)                           \
        a1[mi] = *(const s16x8*)(LDSB + bufR + rdA + (kso) + 4096 + mi * 1024);\
  } while (0)

#define MFMA32()                                                               \
  do {                                                                         \
    _Pragma("unroll") for (int mi = 0; mi < 4; ++mi)                           \
        _Pragma("unroll") for (int ni = 0; ni < 4; ++ni)                       \
            acc[mi][ni] = __builtin_amdgcn_mfma_f32_16x16x32_bf16(             \
                a0[mi], b0[ni], acc[mi][ni], 0, 0, 0);                         \
    _Pragma("unroll") for (int mi = 0; mi < 4; ++mi)                           \
        _Pragma("unroll") for (int ni = 0; ni < 4; ++ni)                       \
            acc[4 + mi][ni] = __builtin_amdgcn_mfma_f32_16x16x32_bf16(         \
                a1[mi], b0[ni], acc[4 + mi][ni], 0, 0, 0);                     \
  } while (0)

#define STAGE(srcbase, bufo, op, h, koff)                                      \
  do {                                                                         \
    __builtin_amdgcn_global_load_lds(                                          \
        AS1((srcbase) + (koff) + (h) * 64),                                    \
        AS3((char*)lds + (bufo) + (op) * 32768 + (h) * 16384 + wv * 1024),     \
        16, 0, 0);                                                             \
    __builtin_amdgcn_global_load_lds(                                          \
        AS1((srcbase) + 128 * Kb + (koff) + (h) * 64),                         \
        AS3((char*)lds + (bufo) + (op) * 32768 + (h) * 16384 + wv * 1024 +     \
            8192),                                                             \
        16, 0, 0);                                                             \
  } while (0)

__global__ void __launch_bounds__(512, 2)
gemm256(const unsigned short* __restrict__ A, const unsigned short* __restrict__ B,
        const float* __restrict__ scale, const float* __restrict__ bias,
        float* __restrict__ C, const int M, const int N, const int K) {
  __shared__ unsigned short lds[65536];  // 128 KiB
  const int tid = threadIdx.x;
  const int lane = tid & 63;
  const int wv = tid >> 6;   // 0..7
  const int wm = wv >> 2;    // 0..1
  const int wn = wv & 3;     // 0..3
  const int lr = lane & 15, lk = lane >> 4;

  // XCD-aware swizzle (bijective: nwg % 8 == 0 for our shape)
  const int mt = M >> 8, nt = N >> 8;
  const int nwg = mt * nt;
  const int orig = blockIdx.x;
  const int wg = (nwg & 7) ? orig : ((orig & 7) * (nwg >> 3) + (orig >> 3));
  const int bm = wg % mt;
  const int bn = wg / mt;
  const int rA0 = bm * 256, rB0 = bn * 256;

  // ds_read per-thread byte bases (swizzled column is per-thread constant)
  const int swc = (lk ^ ((lr >> 1) & 3)) * 16;
  const int rdA = (wm * 128 + lr) * 64 + swc;
  const int rdB = 32768 + (wn * 64 + lr) * 64 + swc;

  // stage per-thread source base (inverse-swizzled)
  const int q = ((wv * 16 + (lane >> 2)) >> 1) & 3;
  const int kc2 = (lane & 3) ^ q;
  const long Kb = (long)K * 2;
  const char* sA0 = (const char*)A + (long)(rA0 + wv * 16 + (lane >> 2)) * Kb + kc2 * 16;
  const char* sB0 = (const char*)B + (long)(rB0 + wv * 16 + (lane >> 2)) * Kb + kc2 * 16;

  // wave role rotation: odd waves consume K-half1 first
  const int o16 = (wv & 1) << 14;  // 0 or 16384

  f32x4 acc[8][4] = {};
  const int NT = K >> 6;

  // prologue: stage full tile 0 into buf0
  STAGE(sA0, 0, 0, 0, 0);
  STAGE(sB0, 0, 1, 0, 0);
  STAGE(sA0, 0, 0, 1, 0);
  STAGE(sB0, 0, 1, 1, 0);
  WAITV0();
  BAR();

  for (int t = 0; t < NT; ++t) {
    const int bufR = (t & 1) * 65536;
    const int bufW = 65536 - bufR;
    const long koff = (long)(t + 1) * 128;

    if (t < NT - 1) {  // stage full tile t+1 (8 wave-loads, retired at tile end)
      STAGE(sA0, bufW, 0, 0, koff);
      STAGE(sB0, bufW, 1, 0, koff);
      STAGE(sA0, bufW, 0, 1, koff);
      STAGE(sB0, bufW, 1, 1, koff);
    }
    {  // sub-step 1: K-half = o
      s16x8 a0[4], b0[4], a1[4];
      LOADSUB(o16);
      PRIO(1); MFMA32(); PRIO(0);
    }
    {  // sub-step 2: K-half = o^1
      s16x8 a0[4], b0[4], a1[4];
      LOADSUB(16384 - o16);
      PRIO(1); MFMA32(); PRIO(0);
    }
    WAITV0();  // retires tile-(t+1) stages issued a full K-tile ago (~free)
    BAR();     // publish buf[t+1]; all waves done reading buf[t]
  }

  // epilogue: C = acc*scale + bias ; C/D layout: col=lane&15, row=(lane>>4)*4+reg
  const float s = scale[0];
  const int n0 = rB0 + wn * 64 + lr;
  float bb[4];
#pragma unroll
  for (int ni = 0; ni < 4; ++ni) bb[ni] = bias[n0 + ni * 16];
#pragma unroll
  for (int mi = 0; mi < 8; ++mi) {
#pragma unroll
    for (int rg = 0; rg < 4; ++rg) {
      float* crow = C + (size_t)(rA0 + wm * 128 + mi * 16 + lk * 4 + rg) * N + n0;
#pragma unroll
      for (int ni = 0; ni < 4; ++ni)
        crow[ni * 16] = acc[mi][ni][rg] * s + bb[ni];
    }
  }
}

// ---------------- round-1 128x128 kernel kept as fallback ----------------
template <bool ABF, bool BBF>
__global__ void __launch_bounds__(256, 2)
gemm_bin(const void* __restrict__ Ap, const void* __restrict__ Bp,
         const float* __restrict__ scale, const float* __restrict__ bias,
         float* __restrict__ C, const int M, const int N, const int K) {
  __shared__ unsigned short As[128 * 64];
  __shared__ unsigned short Bs[128 * 64];
  const int tid = threadIdx.x;
  const int lane = tid & 63;
  const int wv = tid >> 6;
  const int wm = wv >> 1, wn = wv & 1;
  const int bn = blockIdx.x, bm = blockIdx.y;
  const int lr = lane & 15, lk = lane >> 4;
  f32x4 acc[4][4] = {};
  const int rA0 = bm * 128, rB0 = bn * 128;

  for (int k0 = 0; k0 < K; k0 += 64) {
    if constexpr (ABF) {
      const unsigned short* Ag = (const unsigned short*)Ap;
#pragma unroll
      for (int i = 0; i < 4; ++i) {
        const int cbase = i * 256 + wv * 64;
        const int c = cbase + lane;
        const int row = c >> 3, kc = c & 7;
        const int kcs = kc ^ (row & 7);
        const unsigned short* src = Ag + (size_t)(rA0 + row) * K + (k0 + kcs * 8);
        __builtin_amdgcn_global_load_lds(AS1(src), AS3(&As[cbase * 8]), 16, 0, 0);
      }
    } else {
      const float* Ag = (const float*)Ap;
#pragma unroll
      for (int i = 0; i < 4; ++i) {
        const int c = i * 256 + tid;
        const int row = c >> 3, kc = c & 7;
        const f32x4* src = (const f32x4*)(Ag + (size_t)(rA0 + row) * K + (k0 + kc * 8));
        f32x4 v0 = src[0], v1 = src[1];
        s16x8 o;
        o[0] = (short)f2bf(v0[0]); o[1] = (short)f2bf(v0[1]);
        o[2] = (short)f2bf(v0[2]); o[3] = (short)f2bf(v0[3]);
        o[4] = (short)f2bf(v1[0]); o[5] = (short)f2bf(v1[1]);
        o[6] = (short)f2bf(v1[2]); o[7] = (short)f2bf(v1[3]);
        *(s16x8*)&As[(row * 8 + (kc ^ (row & 7))) * 8] = o;
      }
    }
    if constexpr (BBF) {
      const unsigned short* Bg = (const unsigned short*)Bp;
#pragma unroll
      for (int i = 0; i < 4; ++i) {
        const int cbase = i * 256 + wv * 64;
        const int c = cbase + lane;
        const int row = c >> 3, kc = c & 7;
        const int kcs = kc ^ (row & 7);
        const unsigned short* src = Bg + (size_t)(rB0 + row) * K + (k0 + kcs * 8);
        __builtin_amdgcn_global_load_lds(AS1(src), AS3(&Bs[cbase * 8]), 16, 0, 0);
      }
    } else {
      const unsigned int* Bg = (const unsigned int*)Bp;
#pragma unroll
      for (int i = 0; i < 4; ++i) {
        const int c = i * 256 + tid;
        const int row = c >> 3, kc = c & 7;
        const u32x4* src = (const u32x4*)(Bg + (size_t)(rB0 + row) * K + (k0 + kc * 8));
        u32x4 v0 = src[0], v1 = src[1];
        s16x8 o;
        o[0] = (short)(0x3F80u | ((v0[0] >> 16) & 0x8000u));
        o[1] = (short)(0x3F80u | ((v0[1] >> 16) & 0x8000u));
        o[2] = (short)(0x3F80u | ((v0[2] >> 16) & 0x8000u));
        o[3] = (short)(0x3F80u | ((v0[3] >> 16) & 0x8000u));
        o[4] = (short)(0x3F80u | ((v1[0] >> 16) & 0x8000u));
        o[5] = (short)(0x3F80u | ((v1[1] >> 16) & 0x8000u));
        o[6] = (short)(0x3F80u | ((v1[2] >> 16) & 0x8000u));
        o[7] = (short)(0x3F80u | ((v1[3] >> 16) & 0x8000u));
        *(s16x8*)&Bs[(row * 8 + (kc ^ (row & 7))) * 8] = o;
      }
    }
    __syncthreads();
#pragma unroll
    for (int ks = 0; ks < 2; ++ks) {
      s16x8 a[4], b[4];
#pragma unroll
      for (int mi = 0; mi < 4; ++mi) {
        const int row = wm * 64 + mi * 16 + lr;
        const int kc = ks * 4 + lk;
        a[mi] = *(const s16x8*)&As[(row * 8 + (kc ^ (row & 7))) * 8];
      }
#pragma unroll
      for (int ni = 0; ni < 4; ++ni) {
        const int row = wn * 64 + ni * 16 + lr;
        const int kc = ks * 4 + lk;
        b[ni] = *(const s16x8*)&Bs[(row * 8 + (kc ^ (row & 7))) * 8];
      }
#pragma unroll
      for (int mi = 0; mi < 4; ++mi)
#pragma unroll
        for (int ni = 0; ni < 4; ++ni)
          acc[mi][ni] = __builtin_amdgcn_mfma_f32_16x16x32_bf16(a[mi], b[ni],
                                                               acc[mi][ni], 0, 0, 0);
    }
    __syncthreads();
  }

  const float s = scale[0];
  const int n0 = rB0 + wn * 64 + lr;
  const int m0 = rA0 + wm * 64 + lk * 4;
  float bb[4];
#pragma unroll
  for (int ni = 0; ni < 4; ++ni) bb[ni] = bias[n0 + ni * 16];
#pragma unroll
  for (int mi = 0; mi < 4; ++mi) {
#pragma unroll
    for (int r = 0; r < 4; ++r) {
      float* crow = C + (size_t)(m0 + mi * 16 + r) * N + n0;
#pragma unroll
      for (int ni = 0; ni < 4; ++ni)
        crow[ni * 16] = acc[mi][ni][r] * s + bb[ni];
    }
  }
}

extern "C" void kernel_launch(void* const* d_in, const int* in_sizes, int n_in,
                              void* d_out, int out_size, void* d_ws, size_t ws_size,
                              hipStream_t stream) {
  const float* x = (const float*)d_in[0];
  const float* w = (const float*)d_in[1];
  const float* scale = (const float*)d_in[2];
  const float* bias = (const float*)d_in[3];
  float* out = (float*)d_out;

  const int K = 4096;
  const int M = in_sizes[0] / K;  // 8192
  const int N = in_sizes[3];      // 16384

  const size_t needA = (size_t)M * K * sizeof(unsigned short);
  const size_t needB = (size_t)N * K * sizeof(unsigned short);

  if (ws_size >= needA + needB && (M % 256) == 0 && (N % 256) == 0) {
    unsigned short* xb = (unsigned short*)d_ws;
    unsigned short* wb = (unsigned short*)((char*)d_ws + needA);
    cvt_f32_bf16<<<2048, 256, 0, stream>>>(x, xb, (M * K) / 8);
    bin_f32_bf16<<<2048, 256, 0, stream>>>((const unsigned int*)w, wb, (N * K) / 8);
    gemm256<<<dim3((M / 256) * (N / 256)), 512, 0, stream>>>(xb, wb, scale, bias,
                                                             out, M, N, K);
  } else if (ws_size >= needA + needB) {
    unsigned short* xb = (unsigned short*)d_ws;
    unsigned short* wb = (unsigned short*)((char*)d_ws + needA);
    cvt_f32_bf16<<<2048, 256, 0, stream>>>(x, xb, (M * K) / 8);
    bin_f32_bf16<<<2048, 256, 0, stream>>>((const unsigned int*)w, wb, (N * K) / 8);
    gemm_bin<true, true><<<dim3(N / 128, M / 128), 256, 0, stream>>>(
        xb, wb, scale, bias, out, M, N, K);
  } else if (ws_size >= needB) {
    unsigned short* wb = (unsigned short*)d_ws;
    bin_f32_bf16<<<2048, 256, 0, stream>>>((const unsigned int*)w, wb, (N * K) / 8);
    gemm_bin<false, true><<<dim3(N / 128, M / 128), 256, 0, stream>>>(
        x, wb, scale, bias, out, M, N, K);
  } else {
    gemm_bin<false, false><<<dim3(N / 128, M / 128), 256, 0, stream>>>(
        x, w, scale, bias, out, M, N, K);
  }
}

// Round 5
// 1390.104 us; speedup vs baseline: 1.0269x; 1.0269x over previous
//
#include <hip/hip_runtime.h>
#include <hip/hip_bf16.h>

// BinaryLinear: C[M,N] = (x[M,K] @ sign(W)[N,K]^T) * scale + bias
// M=8192 K=4096 N=16384 fp32. Binarize W -> +-1 bf16, round x -> bf16,
// bf16 MFMA GEMM. Round 5: 32x32x16 MFMA (faster pipe, half the inst count),
// clean sub-steps (no setprio/sched_barrier between reads and MFMA so the
// compiler emits counted lgkmcnt and overlaps LDS reads under the MFMA pipe),
// round-3 staging cadence (4 loads/sub-step, counted vmcnt(4), dual buffer).

typedef __attribute__((ext_vector_type(4))) float f32x4;
typedef __attribute__((ext_vector_type(16))) float f32x16;
typedef __attribute__((ext_vector_type(8))) short s16x8;
typedef __attribute__((ext_vector_type(4))) unsigned int u32x4;

#define AS1(p) ((const __attribute__((address_space(1))) void*)(p))
#define AS3(p) ((__attribute__((address_space(3))) void*)(p))

__device__ __forceinline__ unsigned short f2bf(float f) {
  unsigned u = __float_as_uint(f);
  u += 0x7FFFu + ((u >> 16) & 1u);
  return (unsigned short)(u >> 16);
}

__global__ void __launch_bounds__(256) cvt_f32_bf16(const float* __restrict__ in,
                                                    unsigned short* __restrict__ out,
                                                    int n8) {
  int i = blockIdx.x * 256 + threadIdx.x;
  const int stride = gridDim.x * 256;
  for (; i < n8; i += stride) {
    const f32x4* p = (const f32x4*)in + (size_t)i * 2;
    f32x4 v0 = p[0], v1 = p[1];
    s16x8 o;
    o[0] = (short)f2bf(v0[0]); o[1] = (short)f2bf(v0[1]);
    o[2] = (short)f2bf(v0[2]); o[3] = (short)f2bf(v0[3]);
    o[4] = (short)f2bf(v1[0]); o[5] = (short)f2bf(v1[1]);
    o[6] = (short)f2bf(v1[2]); o[7] = (short)f2bf(v1[3]);
    *(s16x8*)(out + (size_t)i * 8) = o;
  }
}

__global__ void __launch_bounds__(256) bin_f32_bf16(const unsigned int* __restrict__ in,
                                                    unsigned short* __restrict__ out,
                                                    int n8) {
  int i = blockIdx.x * 256 + threadIdx.x;
  const int stride = gridDim.x * 256;
  for (; i < n8; i += stride) {
    const u32x4* p = (const u32x4*)in + (size_t)i * 2;
    u32x4 v0 = p[0], v1 = p[1];
    s16x8 o;  // bf16 +-1.0 from fp32 sign bit
    o[0] = (short)(0x3F80u | ((v0[0] >> 16) & 0x8000u));
    o[1] = (short)(0x3F80u | ((v0[1] >> 16) & 0x8000u));
    o[2] = (short)(0x3F80u | ((v0[2] >> 16) & 0x8000u));
    o[3] = (short)(0x3F80u | ((v0[3] >> 16) & 0x8000u));
    o[4] = (short)(0x3F80u | ((v1[0] >> 16) & 0x8000u));
    o[5] = (short)(0x3F80u | ((v1[1] >> 16) & 0x8000u));
    o[6] = (short)(0x3F80u | ((v1[2] >> 16) & 0x8000u));
    o[7] = (short)(0x3F80u | ((v1[3] >> 16) & 0x8000u));
    *(s16x8*)(out + (size_t)i * 8) = o;
  }
}

// ---------------------------------------------------------------------------
// 256x256 tile, BK=64, 512 threads = 8 waves (2M x 4N), wave tile 128x64
// as 4x2 tiles of 32x32 (mfma_f32_32x32x16_bf16, K-step 16).
// LDS (128 KiB): buf{0,1} x op{A,B} x Khalf{0,1} regions of 256 rows x 64 B.
//   region byte = row*64 + (chunk ^ (row&3))*16   (chunk = logical 16B slot)
// Read (frag for k-step ks in half): row = base+ (lane&31), logical chunk =
// ks*2 + (lane>>5) -> stored chunk ^= row&3 = lane&3: per-lane constant.
// Conflict-free: each bank serves exactly 8 lanes per b128 (8-cyc minimum).
// Stage: global_load_lds w=16, linear dest; inverse-swizzled source with
// kc2 = (lane&3) ^ ((lane>>2)&3) (wave-invariant).
// Per sub-step (K-half): [4 staging loads][12 ds_read in consumption order]
// [16 MFMA][vmcnt(4)][barrier]. No setprio/sched_barrier inside.
// ---------------------------------------------------------------------------

#define WAITV4() asm volatile("s_waitcnt vmcnt(4)" ::: "memory")
#define WAITV0() asm volatile("s_waitcnt vmcnt(0)" ::: "memory")
#define BAR()    __builtin_amdgcn_s_barrier()

#define LDSB ((const char*)lds)

#define SUBSTEP(hOfs)                                                          \
  do {                                                                         \
    s16x8 a0[4], a1[4], b0[2], b1[2];                                          \
    a0[0] = *(const s16x8*)(LDSB + bufR + (hOfs) + rdA0);                      \
    b0[0] = *(const s16x8*)(LDSB + bufR + (hOfs) + rdB0);                      \
    b0[1] = *(const s16x8*)(LDSB + bufR + (hOfs) + rdB0 + 2048);               \
    a0[1] = *(const s16x8*)(LDSB + bufR + (hOfs) + rdA0 + 2048);               \
    a0[2] = *(const s16x8*)(LDSB + bufR + (hOfs) + rdA0 + 4096);               \
    a0[3] = *(const s16x8*)(LDSB + bufR + (hOfs) + rdA0 + 6144);               \
    a1[0] = *(const s16x8*)(LDSB + bufR + (hOfs) + rdA1);                      \
    b1[0] = *(const s16x8*)(LDSB + bufR + (hOfs) + rdB1);                      \
    b1[1] = *(const s16x8*)(LDSB + bufR + (hOfs) + rdB1 + 2048);               \
    a1[1] = *(const s16x8*)(LDSB + bufR + (hOfs) + rdA1 + 2048);               \
    a1[2] = *(const s16x8*)(LDSB + bufR + (hOfs) + rdA1 + 4096);               \
    a1[3] = *(const s16x8*)(LDSB + bufR + (hOfs) + rdA1 + 6144);               \
    _Pragma("unroll") for (int mi = 0; mi < 4; ++mi)                           \
        _Pragma("unroll") for (int ni = 0; ni < 2; ++ni)                       \
            acc[mi][ni] = __builtin_amdgcn_mfma_f32_32x32x16_bf16(             \
                a0[mi], b0[ni], acc[mi][ni], 0, 0, 0);                         \
    _Pragma("unroll") for (int mi = 0; mi < 4; ++mi)                           \
        _Pragma("unroll") for (int ni = 0; ni < 2; ++ni)                       \
            acc[mi][ni] = __builtin_amdgcn_mfma_f32_32x32x16_bf16(             \
                a1[mi], b1[ni], acc[mi][ni], 0, 0, 0);                         \
  } while (0)

#define STAGE(srcbase, bufo, op, h, koff)                                      \
  do {                                                                         \
    __builtin_amdgcn_global_load_lds(                                          \
        AS1((srcbase) + (koff) + (h) * 64),                                    \
        AS3((char*)lds + (bufo) + (op) * 32768 + (h) * 16384 + wv * 1024),     \
        16, 0, 0);                                                             \
    __builtin_amdgcn_global_load_lds(                                          \
        AS1((srcbase) + 128 * Kb + (koff) + (h) * 64),                         \
        AS3((char*)lds + (bufo) + (op) * 32768 + (h) * 16384 + wv * 1024 +     \
            8192),                                                             \
        16, 0, 0);                                                             \
  } while (0)

__global__ void __launch_bounds__(512, 2)
gemm256(const unsigned short* __restrict__ A, const unsigned short* __restrict__ B,
        const float* __restrict__ scale, const float* __restrict__ bias,
        float* __restrict__ C, const int M, const int N, const int K) {
  __shared__ unsigned short lds[65536];  // 128 KiB
  const int tid = threadIdx.x;
  const int lane = tid & 63;
  const int wv = tid >> 6;   // 0..7
  const int wm = wv >> 2;    // 0..1
  const int wn = wv & 3;     // 0..3
  const int l31 = lane & 31;

  // XCD-aware swizzle (bijective: nwg % 8 == 0 for our shape)
  const int mt = M >> 8, nt = N >> 8;
  const int nwg = mt * nt;
  const int orig = blockIdx.x;
  const int wg = (nwg & 7) ? orig : ((orig & 7) * (nwg >> 3) + (orig >> 3));
  const int bm = wg % mt;
  const int bn = wg / mt;
  const int rA0 = bm * 256, rB0 = bn * 256;

  // ds_read per-thread byte bases (region-internal). Stored chunk for k-step
  // ks: (ks*2 + (lane>>5)) ^ (row&3), row&3 == lane&3 for all frag rows.
  const int ch0 = (((lane >> 5) ^ (lane & 3))) * 16;  // ks=0
  const int ch1 = ch0 ^ 32;                           // ks=1 (XOR bit1)
  const int rdA0 = (wm * 128 + l31) * 64 + ch0;
  const int rdA1 = (wm * 128 + l31) * 64 + ch1;
  const int rdB0 = 32768 + (wn * 64 + l31) * 64 + ch0;
  const int rdB1 = 32768 + (wn * 64 + l31) * 64 + ch1;

  // stage per-thread source base (inverse-swizzled, wave-invariant)
  const int kc2 = (lane & 3) ^ ((lane >> 2) & 3);
  const long Kb = (long)K * 2;
  const char* sA0 = (const char*)A + (long)(rA0 + wv * 16 + (lane >> 2)) * Kb + kc2 * 16;
  const char* sB0 = (const char*)B + (long)(rB0 + wv * 16 + (lane >> 2)) * Kb + kc2 * 16;

  f32x16 acc[4][2] = {};
  const int NT = K >> 6;

  // prologue: stage tile 0 (h0 group, then h1 group)
  STAGE(sA0, 0, 0, 0, 0);
  STAGE(sB0, 0, 1, 0, 0);
  STAGE(sA0, 0, 0, 1, 0);
  STAGE(sB0, 0, 1, 1, 0);
  WAITV4();  // h0 landed; h1 (4 loads) in flight
  BAR();

  for (int t = 0; t < NT - 1; ++t) {
    const int bufR = (t & 1) * 65536;
    const int bufW = 65536 - bufR;
    const long koff = (long)(t + 1) * 128;

    // ---- sub-step h=0: reads buf[t].h0 (published), stages h0(t+1) ----
    STAGE(sA0, bufW, 0, 0, koff);
    STAGE(sB0, bufW, 1, 0, koff);
    SUBSTEP(0);
    WAITV4();  // outstanding: h1(t)[4] + h0(t+1)[4] -> retire h1(t)
    BAR();     // publish h1(t)

    // ---- sub-step h=1: reads buf[t].h1, stages h1(t+1) ----
    STAGE(sA0, bufW, 0, 1, koff);
    STAGE(sB0, bufW, 1, 1, koff);
    SUBSTEP(16384);
    WAITV4();  // outstanding: h0(t+1)[4] + h1(t+1)[4] -> retire h0(t+1)
    BAR();     // publish h0(t+1)
  }

  // peeled last tile (no stages)
  {
    const int bufR = ((NT - 1) & 1) * 65536;
    SUBSTEP(0);
    WAITV0();  // retire h1(NT-1)
    BAR();
    SUBSTEP(16384);
  }

  // epilogue: C = acc*scale + bias
  // 32x32 C/D layout (m74/m101): col = lane&31, row = (reg&3)+8*(reg>>2)+4*(lane>>5)
  const float s = scale[0];
  const int n0 = rB0 + wn * 64 + l31;
  float bb[2];
  bb[0] = bias[n0];
  bb[1] = bias[n0 + 32];
  const int m0 = rA0 + wm * 128 + ((lane >> 5) << 2);
#pragma unroll
  for (int mi = 0; mi < 4; ++mi) {
#pragma unroll
    for (int ni = 0; ni < 2; ++ni) {
#pragma unroll
      for (int r = 0; r < 16; ++r) {
        const int row = m0 + mi * 32 + (r & 3) + 8 * (r >> 2);
        C[(size_t)row * N + n0 + ni * 32] = acc[mi][ni][r] * s + bb[ni];
      }
    }
  }
}

// ---------------- round-1 128x128 kernel kept as fallback ----------------
template <bool ABF, bool BBF>
__global__ void __launch_bounds__(256, 2)
gemm_bin(const void* __restrict__ Ap, const void* __restrict__ Bp,
         const float* __restrict__ scale, const float* __restrict__ bias,
         float* __restrict__ C, const int M, const int N, const int K) {
  __shared__ unsigned short As[128 * 64];
  __shared__ unsigned short Bs[128 * 64];
  const int tid = threadIdx.x;
  const int lane = tid & 63;
  const int wv = tid >> 6;
  const int wm = wv >> 1, wn = wv & 1;
  const int bn = blockIdx.x, bm = blockIdx.y;
  const int lr = lane & 15, lk = lane >> 4;
  f32x4 acc[4][4] = {};
  const int rA0 = bm * 128, rB0 = bn * 128;

  for (int k0 = 0; k0 < K; k0 += 64) {
    if constexpr (ABF) {
      const unsigned short* Ag = (const unsigned short*)Ap;
#pragma unroll
      for (int i = 0; i < 4; ++i) {
        const int cbase = i * 256 + wv * 64;
        const int c = cbase + lane;
        const int row = c >> 3, kc = c & 7;
        const int kcs = kc ^ (row & 7);
        const unsigned short* src = Ag + (size_t)(rA0 + row) * K + (k0 + kcs * 8);
        __builtin_amdgcn_global_load_lds(AS1(src), AS3(&As[cbase * 8]), 16, 0, 0);
      }
    } else {
      const float* Ag = (const float*)Ap;
#pragma unroll
      for (int i = 0; i < 4; ++i) {
        const int c = i * 256 + tid;
        const int row = c >> 3, kc = c & 7;
        const f32x4* src = (const f32x4*)(Ag + (size_t)(rA0 + row) * K + (k0 + kc * 8));
        f32x4 v0 = src[0], v1 = src[1];
        s16x8 o;
        o[0] = (short)f2bf(v0[0]); o[1] = (short)f2bf(v0[1]);
        o[2] = (short)f2bf(v0[2]); o[3] = (short)f2bf(v0[3]);
        o[4] = (short)f2bf(v1[0]); o[5] = (short)f2bf(v1[1]);
        o[6] = (short)f2bf(v1[2]); o[7] = (short)f2bf(v1[3]);
        *(s16x8*)&As[(row * 8 + (kc ^ (row & 7))) * 8] = o;
      }
    }
    if constexpr (BBF) {
      const unsigned short* Bg = (const unsigned short*)Bp;
#pragma unroll
      for (int i = 0; i < 4; ++i) {
        const int cbase = i * 256 + wv * 64;
        const int c = cbase + lane;
        const int row = c >> 3, kc = c & 7;
        const int kcs = kc ^ (row & 7);
        const unsigned short* src = Bg + (size_t)(rB0 + row) * K + (k0 + kcs * 8);
        __builtin_amdgcn_global_load_lds(AS1(src), AS3(&Bs[cbase * 8]), 16, 0, 0);
      }
    } else {
      const unsigned int* Bg = (const unsigned int*)Bp;
#pragma unroll
      for (int i = 0; i < 4; ++i) {
        const int c = i * 256 + tid;
        const int row = c >> 3, kc = c & 7;
        const u32x4* src = (const u32x4*)(Bg + (size_t)(rB0 + row) * K + (k0 + kc * 8));
        u32x4 v0 = src[0], v1 = src[1];
        s16x8 o;
        o[0] = (short)(0x3F80u | ((v0[0] >> 16) & 0x8000u));
        o[1] = (short)(0x3F80u | ((v0[1] >> 16) & 0x8000u));
        o[2] = (short)(0x3F80u | ((v0[2] >> 16) & 0x8000u));
        o[3] = (short)(0x3F80u | ((v0[3] >> 16) & 0x8000u));
        o[4] = (short)(0x3F80u | ((v1[0] >> 16) & 0x8000u));
        o[5] = (short)(0x3F80u | ((v1[1] >> 16) & 0x8000u));
        o[6] = (short)(0x3F80u | ((v1[2] >> 16) & 0x8000u));
        o[7] = (short)(0x3F80u | ((v1[3] >> 16) & 0x8000u));
        *(s16x8*)&Bs[(row * 8 + (kc ^ (row & 7))) * 8] = o;
      }
    }
    __syncthreads();
#pragma unroll
    for (int ks = 0; ks < 2; ++ks) {
      s16x8 a[4], b[4];
#pragma unroll
      for (int mi = 0; mi < 4; ++mi) {
        const int row = wm * 64 + mi * 16 + lr;
        const int kc = ks * 4 + lk;
        a[mi] = *(const s16x8*)&As[(row * 8 + (kc ^ (row & 7))) * 8];
      }
#pragma unroll
      for (int ni = 0; ni < 4; ++ni) {
        const int row = wn * 64 + ni * 16 + lr;
        const int kc = ks * 4 + lk;
        b[ni] = *(const s16x8*)&Bs[(row * 8 + (kc ^ (row & 7))) * 8];
      }
#pragma unroll
      for (int mi = 0; mi < 4; ++mi)
#pragma unroll
        for (int ni = 0; ni < 4; ++ni)
          acc[mi][ni] = __builtin_amdgcn_mfma_f32_16x16x32_bf16(a[mi], b[ni],
                                                               acc[mi][ni], 0, 0, 0);
    }
    __syncthreads();
  }

  const float s = scale[0];
  const int n0 = rB0 + wn * 64 + lr;
  const int m0 = rA0 + wm * 64 + lk * 4;
  float bb[4];
#pragma unroll
  for (int ni = 0; ni < 4; ++ni) bb[ni] = bias[n0 + ni * 16];
#pragma unroll
  for (int mi = 0; mi < 4; ++mi) {
#pragma unroll
    for (int r = 0; r < 4; ++r) {
      float* crow = C + (size_t)(m0 + mi * 16 + r) * N + n0;
#pragma unroll
      for (int ni = 0; ni < 4; ++ni)
        crow[ni * 16] = acc[mi][ni][r] * s + bb[ni];
    }
  }
}

extern "C" void kernel_launch(void* const* d_in, const int* in_sizes, int n_in,
                              void* d_out, int out_size, void* d_ws, size_t ws_size,
                              hipStream_t stream) {
  const float* x = (const float*)d_in[0];
  const float* w = (const float*)d_in[1];
  const float* scale = (const float*)d_in[2];
  const float* bias = (const float*)d_in[3];
  float* out = (float*)d_out;

  const int K = 4096;
  const int M = in_sizes[0] / K;  // 8192
  const int N = in_sizes[3];      // 16384

  const size_t needA = (size_t)M * K * sizeof(unsigned short);
  const size_t needB = (size_t)N * K * sizeof(unsigned short);

  if (ws_size >= needA + needB && (M % 256) == 0 && (N % 256) == 0) {
    unsigned short* xb = (unsigned short*)d_ws;
    unsigned short* wb = (unsigned short*)((char*)d_ws + needA);
    cvt_f32_bf16<<<2048, 256, 0, stream>>>(x, xb, (M * K) / 8);
    bin_f32_bf16<<<2048, 256, 0, stream>>>((const unsigned int*)w, wb, (N * K) / 8);
    gemm256<<<dim3((M / 256) * (N / 256)), 512, 0, stream>>>(xb, wb, scale, bias,
                                                             out, M, N, K);
  } else if (ws_size >= needA + needB) {
    unsigned short* xb = (unsigned short*)d_ws;
    unsigned short* wb = (unsigned short*)((char*)d_ws + needA);
    cvt_f32_bf16<<<2048, 256, 0, stream>>>(x, xb, (M * K) / 8);
    bin_f32_bf16<<<2048, 256, 0, stream>>>((const unsigned int*)w, wb, (N * K) / 8);
    gemm_bin<true, true><<<dim3(N / 128, M / 128), 256, 0, stream>>>(
        xb, wb, scale, bias, out, M, N, K);
  } else if (ws_size >= needB) {
    unsigned short* wb = (unsigned short*)d_ws;
    bin_f32_bf16<<<2048, 256, 0, stream>>>((const unsigned int*)w, wb, (N * K) / 8);
    gemm_bin<false, true><<<dim3(N / 128, M / 128), 256, 0, stream>>>(
        x, wb, scale, bias, out, M, N, K);
  } else {
    gemm_bin<false, false><<<dim3(N / 128, M / 128), 256, 0, stream>>>(
        x, w, scale, bias, out, M, N, K);
  }
}

// Round 7
// 1292.385 us; speedup vs baseline: 1.1046x; 1.0756x over previous
//
#include <hip/hip_runtime.h>
#include <hip/hip_bf16.h>

// BinaryLinear: C[M,N] = (x[M,K] @ sign(W)[N,K]^T) * scale + bias
// M=8192 K=4096 N=16384 fp32. Binarize W -> +-1 bf16, round x -> bf16,
// bf16 MFMA GEMM. Round 7: R6's m201-style phase schedule with the tail
// FIXED: staging is unconditional (K-offsets wrap mod NT) so the
// outstanding-load queue is identical in every iteration and the fixed
// vmcnt(6) immediates are exact for all t. vmcnt(0) after the loop.

typedef __attribute__((ext_vector_type(4))) float f32x4;
typedef __attribute__((ext_vector_type(8))) short s16x8;
typedef __attribute__((ext_vector_type(4))) unsigned int u32x4;

#define AS1(p) ((const __attribute__((address_space(1))) void*)(p))
#define AS3(p) ((__attribute__((address_space(3))) void*)(p))

__device__ __forceinline__ unsigned short f2bf(float f) {
  unsigned u = __float_as_uint(f);
  u += 0x7FFFu + ((u >> 16) & 1u);
  return (unsigned short)(u >> 16);
}

__global__ void __launch_bounds__(256) cvt_f32_bf16(const float* __restrict__ in,
                                                    unsigned short* __restrict__ out,
                                                    int n8) {
  int i = blockIdx.x * 256 + threadIdx.x;
  const int stride = gridDim.x * 256;
  for (; i < n8; i += stride) {
    const f32x4* p = (const f32x4*)in + (size_t)i * 2;
    f32x4 v0 = p[0], v1 = p[1];
    s16x8 o;
    o[0] = (short)f2bf(v0[0]); o[1] = (short)f2bf(v0[1]);
    o[2] = (short)f2bf(v0[2]); o[3] = (short)f2bf(v0[3]);
    o[4] = (short)f2bf(v1[0]); o[5] = (short)f2bf(v1[1]);
    o[6] = (short)f2bf(v1[2]); o[7] = (short)f2bf(v1[3]);
    *(s16x8*)(out + (size_t)i * 8) = o;
  }
}

__global__ void __launch_bounds__(256) bin_f32_bf16(const unsigned int* __restrict__ in,
                                                    unsigned short* __restrict__ out,
                                                    int n8) {
  int i = blockIdx.x * 256 + threadIdx.x;
  const int stride = gridDim.x * 256;
  for (; i < n8; i += stride) {
    const u32x4* p = (const u32x4*)in + (size_t)i * 2;
    u32x4 v0 = p[0], v1 = p[1];
    s16x8 o;  // bf16 +-1.0 from fp32 sign bit
    o[0] = (short)(0x3F80u | ((v0[0] >> 16) & 0x8000u));
    o[1] = (short)(0x3F80u | ((v0[1] >> 16) & 0x8000u));
    o[2] = (short)(0x3F80u | ((v0[2] >> 16) & 0x8000u));
    o[3] = (short)(0x3F80u | ((v0[3] >> 16) & 0x8000u));
    o[4] = (short)(0x3F80u | ((v1[0] >> 16) & 0x8000u));
    o[5] = (short)(0x3F80u | ((v1[1] >> 16) & 0x8000u));
    o[6] = (short)(0x3F80u | ((v1[2] >> 16) & 0x8000u));
    o[7] = (short)(0x3F80u | ((v1[3] >> 16) & 0x8000u));
    *(s16x8*)(out + (size_t)i * 8) = o;
  }
}

// ---------------------------------------------------------------------------
// 256x256 tile, BK=64, 512 threads = 8 waves (2M x 4N), wave tile 128x64,
// mfma_f32_16x16x32_bf16. LDS (128 KiB): buf{0,1} x regions {A0,A1,B0,B1}
// of 16 KB (256 rows x 64 B = one operand x one K-half).
//   region byte = row*64 + (kc ^ ((row>>1)&3))*16   [verified 0-conflict]
// Phases per K-tile t (16 MFMA each; reads 8/4/4/8); ALL stages
// unconditional with wrapped K-offsets -> every iteration == steady state:
//   ph1: rd A0(t)(8)            stage A1(t+1)  vmcnt(6)  MFMA mi0-3 x b0
//   ph2: rd B1(t)(4)            stage B1(t+1)            MFMA mi4-7 x b0
//   ph3: rd A1lo(t)(4)          stage A0(t+2)  vmcnt(6)  MFMA mi0-3 x b1
//   ph4: rd A1hi(t)(4)+B0(t+1)  stage B0(t+2)            MFMA mi4-7 x b1
// Queue each iter: in [A1(t),B1(t),A0(t+1),B0(t+1)] (8 loads);
// ph1 vmcnt(6) retires A1(t),B1(t); ph3 vmcnt(6) retires A0(t+1),B0(t+1).
// Stage targets' last readers drained >=2 barriers before issue (LGK0 at
// each phase drains that phase's ds_reads before its 2nd barrier).
// ---------------------------------------------------------------------------

#define WAITV6() asm volatile("s_waitcnt vmcnt(6)" ::: "memory")
#define WAITV8() asm volatile("s_waitcnt vmcnt(8)" ::: "memory")
#define WAITV0() asm volatile("s_waitcnt vmcnt(0)" ::: "memory")
#define LGK0()   asm volatile("s_waitcnt lgkmcnt(0)" ::: "memory")
#define BAR()    __builtin_amdgcn_s_barrier()
#define SB0()    __builtin_amdgcn_sched_barrier(0)
#define PRIO(x)  __builtin_amdgcn_s_setprio(x)

#define LDSB ((const char*)lds)

#define STAGE(srcbase, bufo, op, h, koff)                                      \
  do {                                                                         \
    __builtin_amdgcn_global_load_lds(                                          \
        AS1((srcbase) + (koff) + (h) * 64),                                    \
        AS3((char*)lds + (bufo) + (op) * 32768 + (h) * 16384 + wv * 1024),     \
        16, 0, 0);                                                             \
    __builtin_amdgcn_global_load_lds(                                          \
        AS1((srcbase) + 128 * Kb + (koff) + (h) * 64),                         \
        AS3((char*)lds + (bufo) + (op) * 32768 + (h) * 16384 + wv * 1024 +     \
            8192),                                                             \
        16, 0, 0);                                                             \
  } while (0)

#define MFMA16(a, mib, b)                                                      \
  do {                                                                         \
    _Pragma("unroll") for (int mi = 0; mi < 4; ++mi)                           \
        _Pragma("unroll") for (int nj = 0; nj < 4; ++nj)                       \
            acc[(mib) + mi][nj] = __builtin_amdgcn_mfma_f32_16x16x32_bf16(     \
                (a)[mi], (b)[nj], acc[(mib) + mi][nj], 0, 0, 0);               \
  } while (0)

__global__ void __launch_bounds__(512, 2)
gemm256(const unsigned short* __restrict__ A, const unsigned short* __restrict__ B,
        const float* __restrict__ scale, const float* __restrict__ bias,
        float* __restrict__ C, const int M, const int N, const int K) {
  __shared__ unsigned short lds[65536];  // 128 KiB
  const int tid = threadIdx.x;
  const int lane = tid & 63;
  const int wv = tid >> 6;   // 0..7
  const int wm = wv >> 2;    // 0..1
  const int wn = wv & 3;     // 0..3
  const int lr = lane & 15, lk = lane >> 4;

  // XCD-aware swizzle (bijective: nwg % 8 == 0 for our shape)
  const int mt = M >> 8, nt = N >> 8;
  const int nwg = mt * nt;
  const int orig = blockIdx.x;
  const int wg = (nwg & 7) ? orig : ((orig & 7) * (nwg >> 3) + (orig >> 3));
  const int bm = wg % mt;
  const int bn = wg / mt;
  const int rA0 = bm * 256, rB0 = bn * 256;

  // ds_read bases (region-relative; swizzled column is per-lane constant)
  const int swc = (lk ^ ((lr >> 1) & 3)) * 16;
  const int rdA = (wm * 128 + lr) * 64 + swc;             // within A0/A1 region
  const int rdB = (wn * 64 + lr) * 64 + swc;              // within B0/B1 region

  // stage per-thread source base (inverse-swizzled)
  const int kc2 = (lane & 3) ^ ((lane >> 3) & 3);
  const long Kb = (long)K * 2;
  const char* sA0 = (const char*)A + (long)(rA0 + wv * 16 + (lane >> 2)) * Kb + kc2 * 16;
  const char* sB0 = (const char*)B + (long)(rB0 + wv * 16 + (lane >> 2)) * Kb + kc2 * 16;

  f32x4 acc[8][4] = {};
  const int NT = K >> 6;

  // prologue: tile0 {A0,B0,A1,B1}, tile1 {A0,B0}  (12 loads)
  STAGE(sA0, 0, 0, 0, 0);
  STAGE(sB0, 0, 1, 0, 0);
  STAGE(sA0, 0, 0, 1, 0);
  STAGE(sB0, 0, 1, 1, 0);
  STAGE(sA0, 65536, 0, 0, 128);
  STAGE(sB0, 65536, 1, 0, 128);
  WAITV8();  // A0(0),B0(0) landed; queue = [A1(0),B1(0),A0(1),B0(1)]
  BAR();

  s16x8 b0[4];  // lives across iterations: read in ph4(t-1) / prologue
#pragma unroll
  for (int nj = 0; nj < 4; ++nj)
    b0[nj] = *(const s16x8*)(LDSB + 32768 + rdB + nj * 1024);

  for (int t = 0; t < NT; ++t) {
    const int bufR = (t & 1) * 65536;
    const int bufN = 65536 - bufR;
    const int t1 = (t + 1 < NT) ? (t + 1) : 0;            // wrapped
    const int t2 = (t + 2 < NT) ? (t + 2) : (t + 2 - NT); // wrapped
    const long ko1 = (long)t1 * 128;
    const long ko2 = (long)t2 * 128;
    const bool tp1 = (t + 1) < NT;
    s16x8 a0[8], b1[4];

    // ---- phase 1: read A0(t) [8], stage A1(t+1), vmcnt(6) ----
#pragma unroll
    for (int mi = 0; mi < 8; ++mi)
      a0[mi] = *(const s16x8*)(LDSB + bufR + rdA + mi * 1024);
    STAGE(sA0, bufN, 0, 1, ko1);
    WAITV6();  // retires A1(t),B1(t)
    BAR(); LGK0(); SB0();
    PRIO(1); MFMA16(a0, 0, b0); PRIO(0);
    BAR();

    // ---- phase 2: read B1(t) [4], stage B1(t+1) ----
#pragma unroll
    for (int nj = 0; nj < 4; ++nj)
      b1[nj] = *(const s16x8*)(LDSB + bufR + 49152 + rdB + nj * 1024);
    STAGE(sB0, bufN, 1, 1, ko1);
    BAR(); LGK0(); SB0();
    PRIO(1); MFMA16((a0 + 4), 4, b0); PRIO(0);
    BAR();

    // ---- phase 3: read A1-lo(t) [4], stage A0(t+2), vmcnt(6) ----
    {
      s16x8 a1[4];
#pragma unroll
      for (int mi = 0; mi < 4; ++mi)
        a1[mi] = *(const s16x8*)(LDSB + bufR + 16384 + rdA + mi * 1024);
      STAGE(sA0, bufR, 0, 0, ko2);
      WAITV6();  // retires A0(t+1),B0(t+1)
      BAR(); LGK0(); SB0();
      PRIO(1); MFMA16(a1, 0, b1); PRIO(0);
      BAR();
    }

    // ---- phase 4: read A1-hi(t) [4] + B0(t+1) [4], stage B0(t+2) ----
    {
      s16x8 a1b[4];
#pragma unroll
      for (int mi = 0; mi < 4; ++mi)
        a1b[mi] = *(const s16x8*)(LDSB + bufR + 16384 + 4096 + rdA + mi * 1024);
      if (tp1) {
#pragma unroll
        for (int nj = 0; nj < 4; ++nj)
          b0[nj] = *(const s16x8*)(LDSB + bufN + 32768 + rdB + nj * 1024);
      }
      STAGE(sB0, bufR, 1, 0, ko2);
      BAR(); LGK0(); SB0();
      PRIO(1); MFMA16(a1b, 4, b1); PRIO(0);
      BAR();
    }
  }
  WAITV0();  // drain staged loads before wave exit (LDS gets recycled)

  // epilogue: C = acc*scale + bias ; C/D layout: col=lane&15, row=(lane>>4)*4+reg
  const float s = scale[0];
  const int n0 = rB0 + wn * 64 + lr;
  float bb[4];
#pragma unroll
  for (int nj = 0; nj < 4; ++nj) bb[nj] = bias[n0 + nj * 16];
#pragma unroll
  for (int mi = 0; mi < 8; ++mi) {
#pragma unroll
    for (int rg = 0; rg < 4; ++rg) {
      float* crow = C + (size_t)(rA0 + wm * 128 + mi * 16 + lk * 4 + rg) * N + n0;
#pragma unroll
      for (int nj = 0; nj < 4; ++nj)
        crow[nj * 16] = acc[mi][nj][rg] * s + bb[nj];
    }
  }
}

// ---------------- round-1 128x128 kernel kept as fallback ----------------
template <bool ABF, bool BBF>
__global__ void __launch_bounds__(256, 2)
gemm_bin(const void* __restrict__ Ap, const void* __restrict__ Bp,
         const float* __restrict__ scale, const float* __restrict__ bias,
         float* __restrict__ C, const int M, const int N, const int K) {
  __shared__ unsigned short As[128 * 64];
  __shared__ unsigned short Bs[128 * 64];
  const int tid = threadIdx.x;
  const int lane = tid & 63;
  const int wv = tid >> 6;
  const int wm = wv >> 1, wn = wv & 1;
  const int bn = blockIdx.x, bm = blockIdx.y;
  const int lr = lane & 15, lk = lane >> 4;
  f32x4 acc[4][4] = {};
  const int rA0 = bm * 128, rB0 = bn * 128;

  for (int k0 = 0; k0 < K; k0 += 64) {
    if constexpr (ABF) {
      const unsigned short* Ag = (const unsigned short*)Ap;
#pragma unroll
      for (int i = 0; i < 4; ++i) {
        const int cbase = i * 256 + wv * 64;
        const int c = cbase + lane;
        const int row = c >> 3, kc = c & 7;
        const int kcs = kc ^ (row & 7);
        const unsigned short* src = Ag + (size_t)(rA0 + row) * K + (k0 + kcs * 8);
        __builtin_amdgcn_global_load_lds(AS1(src), AS3(&As[cbase * 8]), 16, 0, 0);
      }
    } else {
      const float* Ag = (const float*)Ap;
#pragma unroll
      for (int i = 0; i < 4; ++i) {
        const int c = i * 256 + tid;
        const int row = c >> 3, kc = c & 7;
        const f32x4* src = (const f32x4*)(Ag + (size_t)(rA0 + row) * K + (k0 + kc * 8));
        f32x4 v0 = src[0], v1 = src[1];
        s16x8 o;
        o[0] = (short)f2bf(v0[0]); o[1] = (short)f2bf(v0[1]);
        o[2] = (short)f2bf(v0[2]); o[3] = (short)f2bf(v0[3]);
        o[4] = (short)f2bf(v1[0]); o[5] = (short)f2bf(v1[1]);
        o[6] = (short)f2bf(v1[2]); o[7] = (short)f2bf(v1[3]);
        *(s16x8*)&As[(row * 8 + (kc ^ (row & 7))) * 8] = o;
      }
    }
    if constexpr (BBF) {
      const unsigned short* Bg = (const unsigned short*)Bp;
#pragma unroll
      for (int i = 0; i < 4; ++i) {
        const int cbase = i * 256 + wv * 64;
        const int c = cbase + lane;
        const int row = c >> 3, kc = c & 7;
        const int kcs = kc ^ (row & 7);
        const unsigned short* src = Bg + (size_t)(rB0 + row) * K + (k0 + kcs * 8);
        __builtin_amdgcn_global_load_lds(AS1(src), AS3(&Bs[cbase * 8]), 16, 0, 0);
      }
    } else {
      const unsigned int* Bg = (const unsigned int*)Bp;
#pragma unroll
      for (int i = 0; i < 4; ++i) {
        const int c = i * 256 + tid;
        const int row = c >> 3, kc = c & 7;
        const u32x4* src = (const u32x4*)(Bg + (size_t)(rB0 + row) * K + (k0 + kc * 8));
        u32x4 v0 = src[0], v1 = src[1];
        s16x8 o;
        o[0] = (short)(0x3F80u | ((v0[0] >> 16) & 0x8000u));
        o[1] = (short)(0x3F80u | ((v0[1] >> 16) & 0x8000u));
        o[2] = (short)(0x3F80u | ((v0[2] >> 16) & 0x8000u));
        o[3] = (short)(0x3F80u | ((v0[3] >> 16) & 0x8000u));
        o[4] = (short)(0x3F80u | ((v1[0] >> 16) & 0x8000u));
        o[5] = (short)(0x3F80u | ((v1[1] >> 16) & 0x8000u));
        o[6] = (short)(0x3F80u | ((v1[2] >> 16) & 0x8000u));
        o[7] = (short)(0x3F80u | ((v1[3] >> 16) & 0x8000u));
        *(s16x8*)&Bs[(row * 8 + (kc ^ (row & 7))) * 8] = o;
      }
    }
    __syncthreads();
#pragma unroll
    for (int ks = 0; ks < 2; ++ks) {
      s16x8 a[4], b[4];
#pragma unroll
      for (int mi = 0; mi < 4; ++mi) {
        const int row = wm * 64 + mi * 16 + lr;
        const int kc = ks * 4 + lk;
        a[mi] = *(const s16x8*)&As[(row * 8 + (kc ^ (row & 7))) * 8];
      }
#pragma unroll
      for (int ni = 0; ni < 4; ++ni) {
        const int row = wn * 64 + ni * 16 + lr;
        const int kc = ks * 4 + lk;
        b[ni] = *(const s16x8*)&Bs[(row * 8 + (kc ^ (row & 7))) * 8];
      }
#pragma unroll
      for (int mi = 0; mi < 4; ++mi)
#pragma unroll
        for (int ni = 0; ni < 4; ++ni)
          acc[mi][ni] = __builtin_amdgcn_mfma_f32_16x16x32_bf16(a[mi], b[ni],
                                                               acc[mi][ni], 0, 0, 0);
    }
    __syncthreads();
  }

  const float s = scale[0];
  const int n0 = rB0 + wn * 64 + lr;
  const int m0 = rA0 + wm * 64 + lk * 4;
  float bb[4];
#pragma unroll
  for (int ni = 0; ni < 4; ++ni) bb[ni] = bias[n0 + ni * 16];
#pragma unroll
  for (int mi = 0; mi < 4; ++mi) {
#pragma unroll
    for (int r = 0; r < 4; ++r) {
      float* crow = C + (size_t)(m0 + mi * 16 + r) * N + n0;
#pragma unroll
      for (int ni = 0; ni < 4; ++ni)
        crow[ni * 16] = acc[mi][ni][r] * s + bb[ni];
    }
  }
}

extern "C" void kernel_launch(void* const* d_in, const int* in_sizes, int n_in,
                              void* d_out, int out_size, void* d_ws, size_t ws_size,
                              hipStream_t stream) {
  const float* x = (const float*)d_in[0];
  const float* w = (const float*)d_in[1];
  const float* scale = (const float*)d_in[2];
  const float* bias = (const float*)d_in[3];
  float* out = (float*)d_out;

  const int K = 4096;
  const int M = in_sizes[0] / K;  // 8192
  const int N = in_sizes[3];      // 16384

  const size_t needA = (size_t)M * K * sizeof(unsigned short);
  const size_t needB = (size_t)N * K * sizeof(unsigned short);

  if (ws_size >= needA + needB && (M % 256) == 0 && (N % 256) == 0 && (K % 256) == 0) {
    unsigned short* xb = (unsigned short*)d_ws;
    unsigned short* wb = (unsigned short*)((char*)d_ws + needA);
    cvt_f32_bf16<<<2048, 256, 0, stream>>>(x, xb, (M * K) / 8);
    bin_f32_bf16<<<2048, 256, 0, stream>>>((const unsigned int*)w, wb, (N * K) / 8);
    gemm256<<<dim3((M / 256) * (N / 256)), 512, 0, stream>>>(xb, wb, scale, bias,
                                                             out, M, N, K);
  } else if (ws_size >= needA + needB) {
    unsigned short* xb = (unsigned short*)d_ws;
    unsigned short* wb = (unsigned short*)((char*)d_ws + needA);
    cvt_f32_bf16<<<2048, 256, 0, stream>>>(x, xb, (M * K) / 8);
    bin_f32_bf16<<<2048, 256, 0, stream>>>((const unsigned int*)w, wb, (N * K) / 8);
    gemm_bin<true, true><<<dim3(N / 128, M / 128), 256, 0, stream>>>(
        xb, wb, scale, bias, out, M, N, K);
  } else if (ws_size >= needB) {
    unsigned short* wb = (unsigned short*)d_ws;
    bin_f32_bf16<<<2048, 256, 0, stream>>>((const unsigned int*)w, wb, (N * K) / 8);
    gemm_bin<false, true><<<dim3(N / 128, M / 128), 256, 0, stream>>>(
        x, wb, scale, bias, out, M, N, K);
  } else {
    gemm_bin<false, false><<<dim3(N / 128, M / 128), 256, 0, stream>>>(
        x, w, scale, bias, out, M, N, K);
  }
}